// Round 3
// baseline (1011.513 us; speedup 1.0000x reference)
//
#include <hip/hip_runtime.h>
#include <hip/hip_fp16.h>
#include <stdint.h>

// Problem constants (from reference)
#define NN 100000      // nodes
#define NE 1600000     // edges per set
#define ETOT (NE + NN) // edges + self loops

typedef __attribute__((ext_vector_type(8))) short bf16x8;
typedef __attribute__((ext_vector_type(4))) float f32x4;
typedef __attribute__((ext_vector_type(4))) unsigned short us4;

__device__ __forceinline__ float bf2f(unsigned short u) {
    union { unsigned int i; float f; } x; x.i = ((unsigned int)u) << 16; return x.f;
}
__device__ __forceinline__ unsigned short f2bf(float f) {
    union { float f; unsigned int i; } x; x.f = f;
    unsigned int i = x.i;
    return (unsigned short)((i + 0x7FFFu + ((i >> 16) & 1u)) >> 16);
}

// ---------- CSR build ----------
__global__ void k_init_deg(int* deg0, int* deg1) {
    int i = blockIdx.x * 256 + threadIdx.x;
    if (i < NN) { deg0[i] = 1; deg1[i] = 1; }   // self-loop included
}

// 8 edges/thread, int4 loads, 8 independent atomic chains
__global__ void k_count(const int* col, int* deg) {
    int t = blockIdx.x * 256 + threadIdx.x;
    if (t * 8 >= NE) return;
    int4 a = ((const int4*)col)[t * 2];
    int4 b = ((const int4*)col)[t * 2 + 1];
    atomicAdd(&deg[a.x], 1); atomicAdd(&deg[a.y], 1);
    atomicAdd(&deg[a.z], 1); atomicAdd(&deg[a.w], 1);
    atomicAdd(&deg[b.x], 1); atomicAdd(&deg[b.y], 1);
    atomicAdd(&deg[b.z], 1); atomicAdd(&deg[b.w], 1);
}

// block scans 1024 elems (4/thread); writes inclusive scan into rowptr[i+1]
__global__ void k_scan1(const int* deg, int* rp1, int* bsum) {
    __shared__ int s[256];
    int tid = threadIdx.x;
    int base = blockIdx.x * 1024 + tid * 4;
    int v0 = 0, v1 = 0, v2 = 0, v3 = 0;
    if (base + 0 < NN) v0 = deg[base + 0];
    if (base + 1 < NN) v1 = deg[base + 1];
    if (base + 2 < NN) v2 = deg[base + 2];
    if (base + 3 < NN) v3 = deg[base + 3];
    int sum = v0 + v1 + v2 + v3;
    s[tid] = sum; __syncthreads();
    for (int off = 1; off < 256; off <<= 1) {
        int t = (tid >= off) ? s[tid - off] : 0;
        __syncthreads(); s[tid] += t; __syncthreads();
    }
    int run = s[tid] - sum;
    if (base + 0 < NN) { run += v0; rp1[base + 0] = run; }
    if (base + 1 < NN) { run += v1; rp1[base + 1] = run; }
    if (base + 2 < NN) { run += v2; rp1[base + 2] = run; }
    if (base + 3 < NN) { run += v3; rp1[base + 3] = run; }
    if (tid == 255) bsum[blockIdx.x] = s[255];
}

__global__ void k_scan2(int* bsum, int nb) {  // exclusive scan in-place, nb<=128
    __shared__ int s[128];
    int tid = threadIdx.x;
    int v = (tid < nb) ? bsum[tid] : 0;
    s[tid] = v; __syncthreads();
    for (int off = 1; off < 128; off <<= 1) {
        int t = (tid >= off) ? s[tid - off] : 0;
        __syncthreads(); s[tid] += t; __syncthreads();
    }
    if (tid < nb) bsum[tid] = s[tid] - v;
}

__global__ void k_scan3(int* rowptr, const int* bsum) {
    int tid = threadIdx.x;
    int base = blockIdx.x * 1024 + tid * 4;
    int add = bsum[blockIdx.x];
    #pragma unroll
    for (int i = 0; i < 4; i++) {
        int idx = base + i;
        if (idx < NN) rowptr[idx + 1] += add;
    }
    if (blockIdx.x == 0 && tid == 0) rowptr[0] = 0;
}

// self-loop goes in slot rowptr[c] (payload b=1.0, row=c); also computes dis[]
__global__ void k_self(const int* rowptr, const int* deg, unsigned int* eo,
                       int* cursor, float* dis) {
    int i = blockIdx.x * 256 + threadIdx.x;
    if (i < NN) {
        int p = rowptr[i];
        eo[p] = (unsigned int)i | (0x7FFFu << 17);
        cursor[i] = p + 1;
        dis[i] = rsqrtf((float)deg[i]);
    }
}

// 8 edges/thread: payload = row | (b*32767)<<17, b = min(ew^-0.5, 1)
__global__ void k_fill(const int* er, const int* ec, const float* ew,
                       int* cursor, unsigned int* eo) {
    int t = blockIdx.x * 256 + threadIdx.x;
    if (t * 8 >= NE) return;
    int4 r0 = ((const int4*)er)[t * 2], r1 = ((const int4*)er)[t * 2 + 1];
    int4 c0 = ((const int4*)ec)[t * 2], c1 = ((const int4*)ec)[t * 2 + 1];
    float4 w0 = ((const float4*)ew)[t * 2], w1 = ((const float4*)ew)[t * 2 + 1];
    int r[8] = {r0.x, r0.y, r0.z, r0.w, r1.x, r1.y, r1.z, r1.w};
    int c[8] = {c0.x, c0.y, c0.z, c0.w, c1.x, c1.y, c1.z, c1.w};
    float w[8] = {w0.x, w0.y, w0.z, w0.w, w1.x, w1.y, w1.z, w1.w};
    unsigned int pay[8];
    #pragma unroll
    for (int i = 0; i < 8; i++) {
        float b = fminf(rsqrtf(w[i]), 1.0f);
        pay[i] = (unsigned int)r[i] | ((unsigned int)(b * 32767.f + 0.5f) << 17);
    }
    int p[8];
    #pragma unroll
    for (int i = 0; i < 8; i++) p[i] = atomicAdd(&cursor[c[i]], 1);
    #pragma unroll
    for (int i = 0; i < 8; i++) eo[p[i]] = pay[i];
}

// ---------- packing ----------
// Xc[N][256] bf16 = [x | d2an | 0-pad]; 4 cols/thread
__global__ void k_packx(const float* x, const float* d2, unsigned short* Xc) {
    int idx = blockIdx.x * 256 + threadIdx.x;   // NN*64 total
    if (idx >= NN * 64) return;
    int r = idx >> 6, k4 = (idx & 63) << 2;
    us4 o;
    if (k4 < 128) {
        float4 v = *(const float4*)(x + (size_t)r * 128 + k4);
        o[0] = f2bf(v.x); o[1] = f2bf(v.y); o[2] = f2bf(v.z); o[3] = f2bf(v.w);
    } else {
        #pragma unroll
        for (int i = 0; i < 4; i++) {
            int k = k4 + i;
            float v = (k < 226) ? d2[(size_t)r * 98 + (k - 128)] : 0.f;
            o[i] = f2bf(v);
        }
    }
    *(us4*)(Xc + (size_t)r * 256 + k4) = o;
}

// All weights packed in one dispatch, MFMA B-fragment order:
// Wf[ks][ct][lane][j] = Worig[c][k], k = ks*32 + (lane>>4)*8 + j, c = ct*16 + (lane&15)
__global__ void k_packw(const float* wn1, const float* wn2,
                        const float* w1a, const float* w1b,
                        const float* w2a, const float* w2b,
                        const float* w3a, const float* w3b,
                        const float* w4a, const float* w4b,
                        unsigned short* Wfnode, unsigned short* WfL) {
    int idx = blockIdx.x * 256 + threadIdx.x;   // 65536 + 4*32768 = 196608
    if (idx < 65536) {
        int j = idx & 7, lane = (idx >> 3) & 63, ct = (idx >> 9) & 15, ks = idx >> 13;
        int k = ks * 32 + (lane >> 4) * 8 + j;
        int c = ct * 16 + (lane & 15);
        float v = 0.f;
        if (k < 226) v = (c < 128) ? wn1[c * 226 + k] : wn2[(c - 128) * 226 + k];
        Wfnode[idx] = f2bf(v);
    } else if (idx < 196608) {
        int li = idx - 65536;
        int set = li >> 15, r = li & 32767;
        const float* wa = (set == 0) ? w1a : (set == 1) ? w2a : (set == 2) ? w3a : w4a;
        const float* wb = (set == 0) ? w1b : (set == 1) ? w2b : (set == 2) ? w3b : w4b;
        int j = r & 7, lane = (r >> 3) & 63, ct = (r >> 9) & 7, ks = r >> 12;
        int k = ks * 32 + (lane >> 4) * 8 + j;
        int c = ct * 16 + (lane & 15);
        float v = (k < 128) ? wa[c * 128 + k] : wb[c * 128 + (k - 128)];
        WfL[li] = f2bf(v);
    }
}

// ---------- aggregation: one wave per node, 8-deep ILP ----------
// g1 = sum a_e*S[row_e], g2 = sum b_e*S[row_e]; a_e = dis[r]*dis[c], b from payload
template <int SRST, int SOFF>
__global__ __launch_bounds__(256) void k_agg(const unsigned short* S,
                                             const int* rowptr, const unsigned int* eo,
                                             const float* dis, unsigned short* G) {
    int c = blockIdx.x * 4 + (threadIdx.x >> 6);
    int lane = threadIdx.x & 63;
    if (c >= NN) return;
    float disc = dis[c];
    float a0 = 0.f, a1 = 0.f, b0 = 0.f, b1 = 0.f;
    int jb = rowptr[c], je = rowptr[c + 1];
    const unsigned short* Sb = S + SOFF + lane * 2;
    int j = jb;
    for (; j + 8 <= je; j += 8) {
        unsigned int w[8]; float dr[8]; unsigned int u[8];
        #pragma unroll
        for (int i = 0; i < 8; i++) w[i] = eo[j + i];
        #pragma unroll
        for (int i = 0; i < 8; i++) dr[i] = dis[w[i] & 0x1FFFF];
        #pragma unroll
        for (int i = 0; i < 8; i++)
            u[i] = *(const unsigned int*)(Sb + (size_t)(w[i] & 0x1FFFF) * SRST);
        #pragma unroll
        for (int i = 0; i < 8; i++) {
            float a = dr[i] * disc;
            float b = (float)(w[i] >> 17) * (1.0f / 32767.0f);
            float x0 = bf2f((unsigned short)(u[i] & 0xFFFF));
            float x1 = bf2f((unsigned short)(u[i] >> 16));
            a0 += a * x0; a1 += a * x1; b0 += b * x0; b1 += b * x1;
        }
    }
    for (; j + 4 <= je; j += 4) {
        unsigned int w[4]; float dr[4]; unsigned int u[4];
        #pragma unroll
        for (int i = 0; i < 4; i++) w[i] = eo[j + i];
        #pragma unroll
        for (int i = 0; i < 4; i++) dr[i] = dis[w[i] & 0x1FFFF];
        #pragma unroll
        for (int i = 0; i < 4; i++)
            u[i] = *(const unsigned int*)(Sb + (size_t)(w[i] & 0x1FFFF) * SRST);
        #pragma unroll
        for (int i = 0; i < 4; i++) {
            float a = dr[i] * disc;
            float b = (float)(w[i] >> 17) * (1.0f / 32767.0f);
            float x0 = bf2f((unsigned short)(u[i] & 0xFFFF));
            float x1 = bf2f((unsigned short)(u[i] >> 16));
            a0 += a * x0; a1 += a * x1; b0 += b * x0; b1 += b * x1;
        }
    }
    for (; j < je; j++) {
        unsigned int w = eo[j];
        int r = w & 0x1FFFF;
        float a = dis[r] * disc;
        float b = (float)(w >> 17) * (1.0f / 32767.0f);
        unsigned int u = *(const unsigned int*)(Sb + (size_t)r * SRST);
        float x0 = bf2f((unsigned short)(u & 0xFFFF));
        float x1 = bf2f((unsigned short)(u >> 16));
        a0 += a * x0; a1 += a * x1; b0 += b * x0; b1 += b * x1;
    }
    unsigned int* gd = (unsigned int*)(G + (size_t)c * 256);
    gd[lane]      = (unsigned int)f2bf(a0) | ((unsigned int)f2bf(a1) << 16);
    gd[64 + lane] = (unsigned int)f2bf(b0) | ((unsigned int)f2bf(b1) << 16);
}

// ---------- GEMM: C[64 x 128-per-blockIdx.y] = A[N][256] @ Wf, no LDS ----------
// MODE 0: store bf16 plain; 1: store bf16 0.5*relu(T)+0.5*relu(acc); 2: same but f32 to out
template <int MODE>
__global__ __launch_bounds__(256) void k_gemm(const unsigned short* A, int arst,
                                              const unsigned short* Wf, int nct_total,
                                              unsigned short* outB, float* outF,
                                              const unsigned short* T, int orst) {
    int wave = threadIdx.x >> 6, lane = threadIdx.x & 63;
    int m = lane & 15, quad = lane >> 4;
    int row0 = blockIdx.x * 64 + wave * 16;
    int arow = row0 + m;
    bool rowok = arow < NN;
    const unsigned short* Ap = A + (size_t)arow * arst + quad * 8;
    int ctbase = blockIdx.y * 8;
    f32x4 acc[8];
    #pragma unroll
    for (int t = 0; t < 8; t++) acc[t] = (f32x4){0.f, 0.f, 0.f, 0.f};

    #pragma unroll
    for (int ks = 0; ks < 8; ks++) {
        bf16x8 a;
        if (rowok) a = *(const bf16x8*)(Ap + ks * 32);
        else       a = (bf16x8){0, 0, 0, 0, 0, 0, 0, 0};
        const unsigned short* wp = Wf + ((size_t)(ks * nct_total + ctbase) * 64 + lane) * 8;
        #pragma unroll
        for (int t = 0; t < 8; t++) {
            bf16x8 b = *(const bf16x8*)(wp + t * 512);
            acc[t] = __builtin_amdgcn_mfma_f32_16x16x32_bf16(a, b, acc[t], 0, 0, 0);
        }
    }

    int col0 = blockIdx.y * 128;
    #pragma unroll
    for (int t = 0; t < 8; t++) {
        int c = col0 + t * 16 + m;
        #pragma unroll
        for (int rg = 0; rg < 4; rg++) {
            int r = row0 + quad * 4 + rg;
            if (r < NN) {
                float v = acc[t][rg];
                if (MODE == 0) {
                    outB[(size_t)r * orst + c] = f2bf(v);
                } else {
                    float tv = bf2f(T[(size_t)r * 128 + c]);
                    float o = 0.5f * fmaxf(tv, 0.f) + 0.5f * fmaxf(v, 0.f);
                    if (MODE == 1) outB[(size_t)r * orst + c] = f2bf(o);
                    else           outF[(size_t)r * 128 + c] = o;
                }
            }
        }
    }
}

extern "C" void kernel_launch(void* const* d_in, const int* in_sizes, int n_in,
                              void* d_out, int out_size, void* d_ws, size_t ws_size,
                              hipStream_t stream) {
    const float* x      = (const float*)d_in[0];
    const float* d2an   = (const float*)d_in[1];
    const int*   ei0    = (const int*)d_in[2];
    const float* ew0    = (const float*)d_in[3];
    const int*   ei1    = (const int*)d_in[4];
    const float* ew1    = (const float*)d_in[5];
    const float* nodeW1 = (const float*)d_in[6];
    const float* nodeW2 = (const float*)d_in[7];
    const float* W1a = (const float*)d_in[8],  *W1b = (const float*)d_in[9];
    const float* W2a = (const float*)d_in[10], *W2b = (const float*)d_in[11];
    const float* W3a = (const float*)d_in[12], *W3b = (const float*)d_in[13];
    const float* W4a = (const float*)d_in[14], *W4b = (const float*)d_in[15];
    float* out = (float*)d_out;

    // ws carve-out
    char* p = (char*)d_ws;
    auto alloc = [&](size_t bytes) -> char* {
        char* r = p; p += (bytes + 255) & ~(size_t)255; return r;
    };
    unsigned short* bufA   = (unsigned short*)alloc((size_t)NN * 256 * 2); // Xc -> G
    unsigned short* bufB   = (unsigned short*)alloc((size_t)NN * 256 * 2); // P  -> XM
    unsigned short* Tbuf   = (unsigned short*)alloc((size_t)NN * 128 * 2);
    unsigned short* Wfnode = (unsigned short*)alloc(65536 * 2);
    unsigned short* WfL    = (unsigned short*)alloc((size_t)4 * 32768 * 2);
    int*    deg0    = (int*)alloc((size_t)NN * 4);
    int*    deg1    = (int*)alloc((size_t)NN * 4);
    int*    rowptr0 = (int*)alloc((size_t)(NN + 1) * 4);
    int*    rowptr1 = (int*)alloc((size_t)(NN + 1) * 4);
    int*    cursor  = (int*)alloc((size_t)NN * 4);
    int*    bsum    = (int*)alloc(512);
    float*  dis0    = (float*)alloc((size_t)NN * 4);
    float*  dis1    = (float*)alloc((size_t)NN * 4);
    unsigned int* eo0 = (unsigned int*)alloc((size_t)ETOT * 4);
    unsigned int* eo1 = (unsigned int*)alloc((size_t)ETOT * 4);

    int nbN  = (NN + 255) / 256;
    int nbE8 = (NE / 8 + 255) / 256;      // 8 edges/thread
    int nbS  = (NN + 1023) / 1024;        // 98 scan blocks
    dim3 gP((NN + 63) / 64, 2);           // P gemm: 256 output cols
    dim3 gL((NN + 63) / 64, 1);           // layer gemms: 128 output cols
    int nbA = (NN + 3) / 4;               // agg: 4 waves/block, 1 wave/node

    // --- CSR build (per edge set) ---
    k_init_deg<<<nbN, 256, 0, stream>>>(deg0, deg1);
    k_count<<<nbE8, 256, 0, stream>>>(ei0 + NE, deg0);
    k_count<<<nbE8, 256, 0, stream>>>(ei1 + NE, deg1);
    k_scan1<<<nbS, 256, 0, stream>>>(deg0, rowptr0 + 1, bsum);
    k_scan2<<<1, 128, 0, stream>>>(bsum, nbS);
    k_scan3<<<nbS, 256, 0, stream>>>(rowptr0, bsum);
    k_scan1<<<nbS, 256, 0, stream>>>(deg1, rowptr1 + 1, bsum);
    k_scan2<<<1, 128, 0, stream>>>(bsum, nbS);
    k_scan3<<<nbS, 256, 0, stream>>>(rowptr1, bsum);
    k_self<<<nbN, 256, 0, stream>>>(rowptr0, deg0, eo0, cursor, dis0);
    k_fill<<<nbE8, 256, 0, stream>>>(ei0, ei0 + NE, ew0, cursor, eo0);
    k_self<<<nbN, 256, 0, stream>>>(rowptr1, deg1, eo1, cursor, dis1);
    k_fill<<<nbE8, 256, 0, stream>>>(ei1, ei1 + NE, ew1, cursor, eo1);

    // --- packing ---
    k_packx<<<(NN * 64 + 255) / 256, 256, 0, stream>>>(x, d2an, bufA);
    k_packw<<<768, 256, 0, stream>>>(nodeW1, nodeW2, W1a, W1b, W2a, W2b,
                                     W3a, W3b, W4a, W4b, Wfnode, WfL);

    // --- round 1: P = [x|d2an] @ [nodeW1|nodeW2]^T  (bufA=Xc -> bufB=P) ---
    k_gemm<0><<<gP, 256, 0, stream>>>(bufA, 256, Wfnode, 16, bufB, nullptr, nullptr, 256);
    // layer0 (set0 on x0p): agg -> G(bufA); T = g1@W1a^T+g2@W1b^T
    k_agg<256, 0><<<nbA, 256, 0, stream>>>(bufB, rowptr0, eo0, dis0, bufA);
    k_gemm<0><<<gL, 256, 0, stream>>>(bufA, 256, WfL, 8, Tbuf, nullptr, nullptr, 128);
    // layer1 (set1 on x1p): agg -> G(bufA); XM = 0.5relu(T)+0.5relu(g@W2) -> bufB
    k_agg<256, 128><<<nbA, 256, 0, stream>>>(bufB, rowptr1, eo1, dis1, bufA);
    k_gemm<1><<<gL, 256, 0, stream>>>(bufA, 256, WfL + 32768, 8, bufB, nullptr, Tbuf, 128);

    // --- round 2 on XM (bufB, stride 128) ---
    k_agg<128, 0><<<nbA, 256, 0, stream>>>(bufB, rowptr0, eo0, dis0, bufA);
    k_gemm<0><<<gL, 256, 0, stream>>>(bufA, 256, WfL + 2 * 32768, 8, Tbuf, nullptr, nullptr, 128);
    k_agg<128, 0><<<nbA, 256, 0, stream>>>(bufB, rowptr1, eo1, dis1, bufA);
    k_gemm<2><<<gL, 256, 0, stream>>>(bufA, 256, WfL + 3 * 32768, 8, nullptr, out, Tbuf, 128);
}